// Round 3
// baseline (244.108 us; speedup 1.0000x reference)
//
#include <hip/hip_runtime.h>

#define EPSF 1e-12f
#define NKNOTS 30
#define NINT 29

typedef float fvec4 __attribute__((ext_vector_type(4)));

// Uniform knots linspace(0,1,30): idx = floor(x*29), t = x*29 - idx.
// Per-interval cubic y = a0 + t*(a1 + t*(a2 + t*a3)), coefficients in SoA LDS
// arrays (29 entries < 32 banks => ds_read_b32 gathers are conflict-free).

__global__ __launch_bounds__(256) void SimpleSpline_kernel(
    const float* __restrict__ x,
    const float* __restrict__ knots,
    const float* __restrict__ coeffs,
    float* __restrict__ out,
    int n)
{
    __shared__ float a0[NINT], a1[NINT], a2[NINT], a3[NINT];
    __shared__ float dsh[NKNOTS];

    const int tid = threadIdx.x;

    // ---- PCHIP slopes d[tid] (replicates reference math) ----
    if (tid < NKNOTS) {
        float d;
        if (tid == 0) {
            float h0 = knots[1] - knots[0];
            float h1 = knots[2] - knots[1];
            float de0 = (coeffs[1] - coeffs[0]) / (h0 + EPSF);
            float de1 = (coeffs[2] - coeffs[1]) / (h1 + EPSF);
            d = ((2.0f * h0 + h1) * de0 - h0 * de1) / (h0 + h1 + EPSF);
            if (d * de0 <= 0.0f) d = 0.0f;
            if (fabsf(d) > 3.0f * fabsf(de0)) d = 3.0f * de0;
        } else if (tid == NKNOTS - 1) {
            float hN = knots[NKNOTS - 1] - knots[NKNOTS - 2];
            float hM = knots[NKNOTS - 2] - knots[NKNOTS - 3];
            float deN = (coeffs[NKNOTS - 1] - coeffs[NKNOTS - 2]) / (hN + EPSF);
            float deM = (coeffs[NKNOTS - 2] - coeffs[NKNOTS - 3]) / (hM + EPSF);
            d = ((2.0f * hN + hM) * deN - hN * deM) / (hN + hM + EPSF);
            if (d * deN <= 0.0f) d = 0.0f;
            if (fabsf(d) > 3.0f * fabsf(deN)) d = 3.0f * deN;
        } else {
            float hkm1 = knots[tid] - knots[tid - 1];
            float hk   = knots[tid + 1] - knots[tid];
            float dkm1 = (coeffs[tid] - coeffs[tid - 1]) / (hkm1 + EPSF);
            float dk   = (coeffs[tid + 1] - coeffs[tid]) / (hk + EPSF);
            float w1 = 2.0f * hk + hkm1;
            float w2 = hk + 2.0f * hkm1;
            d = 0.0f;
            if (dkm1 * dk > 0.0f)
                d = (w1 + w2) / (w1 / (dkm1 + EPSF) + w2 / (dk + EPSF));
        }
        dsh[tid] = d;
    }
    __syncthreads();

    // ---- per-interval Hermite -> cubic-in-t coefficients (SoA) ----
    if (tid < NINT) {
        float h = knots[tid + 1] - knots[tid];
        float safe_h = (fabsf(h) < EPSF) ? 1.0f : h;
        float yk  = coeffs[tid];
        float yk1 = coeffs[tid + 1];
        float sdk  = safe_h * dsh[tid];
        float sdk1 = safe_h * dsh[tid + 1];
        a0[tid] = yk;
        a1[tid] = sdk;
        a2[tid] = 3.0f * (yk1 - yk) - 2.0f * sdk - sdk1;
        a3[tid] = 2.0f * (yk - yk1) + sdk + sdk1;
    }
    __syncthreads();

    auto eval1 = [&](float xc) -> float {
        xc = fminf(fmaxf(xc, 0.0f), 1.0f);
        float s = xc * 29.0f;
        int idx = (int)s;                      // trunc == floor, s >= 0
        idx = idx > (NINT - 1) ? (NINT - 1) : idx;
        float t = s - (float)idx;
        float c0 = a0[idx], c1 = a1[idx], c2 = a2[idx], c3 = a3[idx];
        return fmaf(t, fmaf(t, fmaf(t, c3, c2), c1), c0);
    };

    auto eval4 = [&](fvec4 v) -> fvec4 {
        fvec4 r;
        r.x = eval1(v.x);
        r.y = eval1(v.y);
        r.z = eval1(v.z);
        r.w = eval1(v.w);
        return r;
    };

    const int n4 = n >> 2;
    const fvec4* __restrict__ xv = (const fvec4*)x;
    fvec4* __restrict__ ov = (fvec4*)out;

    const int gs = gridDim.x * blockDim.x;
    int i = blockIdx.x * blockDim.x + tid;

    // main loop: 4 independent float4 loads in flight per iteration
    for (; i + 3 * gs < n4; i += 4 * gs) {
        fvec4 v0 = xv[i];
        fvec4 v1 = xv[i + gs];
        fvec4 v2 = xv[i + 2 * gs];
        fvec4 v3 = xv[i + 3 * gs];
        fvec4 r0 = eval4(v0);
        fvec4 r1 = eval4(v1);
        fvec4 r2 = eval4(v2);
        fvec4 r3 = eval4(v3);
        __builtin_nontemporal_store(r0, &ov[i]);
        __builtin_nontemporal_store(r1, &ov[i + gs]);
        __builtin_nontemporal_store(r2, &ov[i + 2 * gs]);
        __builtin_nontemporal_store(r3, &ov[i + 3 * gs]);
    }
    // remainder float4s
    for (; i < n4; i += gs) {
        __builtin_nontemporal_store(eval4(xv[i]), &ov[i]);
    }

    // scalar tail (n % 4)
    const int rem = n & 3;
    if (rem) {
        const int base = n4 << 2;
        const int gi = blockIdx.x * blockDim.x + tid;
        if (gi < rem) out[base + gi] = eval1(x[base + gi]);
    }
}

extern "C" void kernel_launch(void* const* d_in, const int* in_sizes, int n_in,
                              void* d_out, int out_size, void* d_ws, size_t ws_size,
                              hipStream_t stream) {
    const float* x      = (const float*)d_in[0];
    const float* knots  = (const float*)d_in[1];
    const float* coeffs = (const float*)d_in[2];
    float* out = (float*)d_out;
    const int n = in_sizes[0];

    const int block = 256;
    int n4 = n >> 2;
    int blocks = (n4 + block - 1) / block;
    if (blocks > 4096) blocks = 4096;
    if (blocks < 1) blocks = 1;

    SimpleSpline_kernel<<<blocks, block, 0, stream>>>(x, knots, coeffs, out, n);
}

// Round 4
// 230.245 us; speedup vs baseline: 1.0602x; 1.0602x over previous
//
#include <hip/hip_runtime.h>

#define EPSF 1e-12f
#define NKNOTS 30
#define NINT 29

typedef float fvec4 __attribute__((ext_vector_type(4)));

// Uniform knots linspace(0,1,30): s = clamp(x*29, 0, 29), idx = min((int)s, 28),
// t = s - idx. Per-interval cubic y = a0 + t*(a1 + t*(a2 + t*a3)), coefficients
// in SoA LDS arrays (29 entries < 32 banks => ds_read_b32 gathers conflict-free;
// duplicate idx within a wave broadcasts).
// One float4 per thread, flat grid: maximize TLP, shortest dependency chain.

__global__ __launch_bounds__(256) void SimpleSpline_kernel(
    const float* __restrict__ x,
    const float* __restrict__ knots,
    const float* __restrict__ coeffs,
    float* __restrict__ out,
    int n)
{
    __shared__ float a0[NINT], a1[NINT], a2[NINT], a3[NINT];
    __shared__ float dsh[NKNOTS];

    const int tid = threadIdx.x;

    // ---- PCHIP slopes d[tid] (replicates reference math) ----
    if (tid < NKNOTS) {
        float d;
        if (tid == 0) {
            float h0 = knots[1] - knots[0];
            float h1 = knots[2] - knots[1];
            float de0 = (coeffs[1] - coeffs[0]) / (h0 + EPSF);
            float de1 = (coeffs[2] - coeffs[1]) / (h1 + EPSF);
            d = ((2.0f * h0 + h1) * de0 - h0 * de1) / (h0 + h1 + EPSF);
            if (d * de0 <= 0.0f) d = 0.0f;
            if (fabsf(d) > 3.0f * fabsf(de0)) d = 3.0f * de0;
        } else if (tid == NKNOTS - 1) {
            float hN = knots[NKNOTS - 1] - knots[NKNOTS - 2];
            float hM = knots[NKNOTS - 2] - knots[NKNOTS - 3];
            float deN = (coeffs[NKNOTS - 1] - coeffs[NKNOTS - 2]) / (hN + EPSF);
            float deM = (coeffs[NKNOTS - 2] - coeffs[NKNOTS - 3]) / (hM + EPSF);
            d = ((2.0f * hN + hM) * deN - hN * deM) / (hN + hM + EPSF);
            if (d * deN <= 0.0f) d = 0.0f;
            if (fabsf(d) > 3.0f * fabsf(deN)) d = 3.0f * deN;
        } else {
            float hkm1 = knots[tid] - knots[tid - 1];
            float hk   = knots[tid + 1] - knots[tid];
            float dkm1 = (coeffs[tid] - coeffs[tid - 1]) / (hkm1 + EPSF);
            float dk   = (coeffs[tid + 1] - coeffs[tid]) / (hk + EPSF);
            float w1 = 2.0f * hk + hkm1;
            float w2 = hk + 2.0f * hkm1;
            d = 0.0f;
            if (dkm1 * dk > 0.0f)
                d = (w1 + w2) / (w1 / (dkm1 + EPSF) + w2 / (dk + EPSF));
        }
        dsh[tid] = d;
    }
    __syncthreads();

    // ---- per-interval Hermite -> cubic-in-t coefficients (SoA) ----
    if (tid < NINT) {
        float h = knots[tid + 1] - knots[tid];
        float safe_h = (fabsf(h) < EPSF) ? 1.0f : h;
        float yk  = coeffs[tid];
        float yk1 = coeffs[tid + 1];
        float sdk  = safe_h * dsh[tid];
        float sdk1 = safe_h * dsh[tid + 1];
        a0[tid] = yk;
        a1[tid] = sdk;
        a2[tid] = 3.0f * (yk1 - yk) - 2.0f * sdk - sdk1;
        a3[tid] = 2.0f * (yk - yk1) + sdk + sdk1;
    }
    __syncthreads();

    auto eval1 = [&](float xi) -> float {
        float s = fminf(fmaxf(xi * 29.0f, 0.0f), 29.0f);
        int idx = (int)s;                      // trunc == floor, s >= 0
        idx = idx > (NINT - 1) ? (NINT - 1) : idx;
        float t = s - (float)idx;
        float c0 = a0[idx], c1 = a1[idx], c2 = a2[idx], c3 = a3[idx];
        return fmaf(t, fmaf(t, fmaf(t, c3, c2), c1), c0);
    };

    const int n4 = n >> 2;
    const int gi = blockIdx.x * blockDim.x + tid;

    if (gi < n4) {
        const fvec4* __restrict__ xv = (const fvec4*)x;
        fvec4* __restrict__ ov = (fvec4*)out;
        fvec4 v = xv[gi];
        fvec4 r;
        r.x = eval1(v.x);
        r.y = eval1(v.y);
        r.z = eval1(v.z);
        r.w = eval1(v.w);
        ov[gi] = r;
    }

    // scalar tail (n % 4)
    const int rem = n & 3;
    if (rem) {
        const int base = n4 << 2;
        if (gi < rem) out[base + gi] = eval1(x[base + gi]);
    }
}

extern "C" void kernel_launch(void* const* d_in, const int* in_sizes, int n_in,
                              void* d_out, int out_size, void* d_ws, size_t ws_size,
                              hipStream_t stream) {
    const float* x      = (const float*)d_in[0];
    const float* knots  = (const float*)d_in[1];
    const float* coeffs = (const float*)d_in[2];
    float* out = (float*)d_out;
    const int n = in_sizes[0];

    const int block = 256;
    int n4 = n >> 2;
    int blocks = (n4 + block - 1) / block;
    if (blocks < 1) blocks = 1;

    SimpleSpline_kernel<<<blocks, block, 0, stream>>>(x, knots, coeffs, out, n);
}